// Round 1
// 783.278 us; speedup vs baseline: 1.9589x; 1.9589x over previous
//
#include <hip/hip_runtime.h>
#include <hip/hip_bf16.h>

using bf16 = __hip_bfloat16;
typedef short short8  __attribute__((ext_vector_type(8)));   // 8 bf16 (4 VGPRs) MFMA frag
typedef short short4v __attribute__((ext_vector_type(4)));
typedef float f32x4   __attribute__((ext_vector_type(4)));   // MFMA accumulator

static __device__ __forceinline__ float b2f(bf16 v){ return __bfloat162float(v); }
static __device__ __forceinline__ bf16  f2b(float v){ return __float2bfloat16(v); }
static __device__ __forceinline__ float s2f(short s){ return __bfloat162float(__builtin_bit_cast(bf16, s)); }
static __device__ __forceinline__ short f2s(float f){ return __builtin_bit_cast(short, __float2bfloat16(f)); }

// fallback path: load 8 consecutive fp32 weights -> bf16x8 MFMA fragment
static __device__ __forceinline__ short8 ldw8(const float* __restrict__ p){
  const float4 u = *(const float4*)(p);
  const float4 v = *(const float4*)(p + 4);
  short8 r;
  r[0]=f2s(u.x); r[1]=f2s(u.y); r[2]=f2s(u.z); r[3]=f2s(u.w);
  r[4]=f2s(v.x); r[5]=f2s(v.y); r[6]=f2s(v.z); r[7]=f2s(v.w);
  return r;
}

#define MFMA16(a,b,c) __builtin_amdgcn_mfma_f32_16x16x32_bf16((a),(b),(c),0,0,0)

constexpr int TPB = 256;
constexpr float EPS = 1e-5f;
constexpr float QSC = 0.17677669529663687f;   // 32^-0.5

// ---- d_ws layout: pre-converted bf16 weights + dense rel-pos bias table
constexpr int WQ_OFF  = 0;        // qkvw  288x96 bf16
constexpr int WPJ_OFF = 27648;    // projw  96x96
constexpr int WF1_OFF = 36864;    // fc1w  192x96
constexpr int WF2_OFF = 55296;    // fc2w  96x192
constexpr int WTOT    = 73728;    // total bf16 weight elements
constexpr int BTAB_BYTE_OFF = 147456;          // fp32 [3][64][64]
constexpr size_t WS_NEEDED = 147456 + 49152;   // 196,608 B

// ---- LDS layout (byte offsets). All row strides multiples of 16B for b128 frag ops.
constexpr int A_OFF = 0;       // s_a  [64][104] bf16; s_at [96][68] (fc2 out, transposed)
constexpr int B_OFF = 13312;   // s_ao [64][104] bf16: attn-out; s_h [64][200] (fc1 out) spans B..E
constexpr int C_OFF = 26624;   // q  [64][40]
constexpr int D_OFF = 31744;   // k  [64][40]
constexpr int E_OFF = 36864;   // vt [32][72]  (V^T: [d][token])
constexpr int F_OFF = 41472;   // P  [64][72]
constexpr int SMEM_BYTES = 50688;   // *3 = 152,064 <= 163,840 -> 3 blocks/CU

__global__ void init_ws_kernel(
    const float* __restrict__ qkvw, const float* __restrict__ projw,
    const float* __restrict__ fc1w, const float* __restrict__ fc2w,
    const float* __restrict__ rpb,
    bf16* __restrict__ wbf, float* __restrict__ btab)
{
  const int i = blockIdx.x * 256 + threadIdx.x;
  if (i < WTOT){
    float v;
    if (i < WPJ_OFF)      v = qkvw[i];
    else if (i < WF1_OFF) v = projw[i - WPJ_OFF];
    else if (i < WF2_OFF) v = fc1w[i - WF1_OFF];
    else                  v = fc2w[i - WF2_OFF];
    wbf[i] = f2b(v);
  }
  if (i < 3*64*64){
    const int h   = i >> 12;
    const int row = (i >> 6) & 63;
    const int col = i & 63;
    const int rel = ((row>>3) - (col>>3) + 7)*15 + ((row&7) - (col&7) + 7);
    btab[i] = rpb[rel*3 + h];
  }
}

template<bool PRE>
__global__ __launch_bounds__(TPB, 3) void swin_block_kernel(
    const float* __restrict__ x,
    const float* __restrict__ qkvw,  const float* __restrict__ qkvb,
    const float* __restrict__ projw, const float* __restrict__ projb,
    const float* __restrict__ rpb,
    const float* __restrict__ n1g,   const float* __restrict__ n1b,
    const float* __restrict__ n2g,   const float* __restrict__ n2b,
    const float* __restrict__ fc1w,  const float* __restrict__ fc1b,
    const float* __restrict__ fc2w,  const float* __restrict__ fc2b,
    float* __restrict__ out,
    const bf16* __restrict__ wbf,    const float* __restrict__ btab)
{
  __shared__ alignas(16) unsigned char smem[SMEM_BYTES];
  bf16* s_a  = (bf16*)(smem + A_OFF);   // stride 104
  bf16* s_ao = (bf16*)(smem + B_OFF);   // stride 104
  bf16* s_q  = (bf16*)(smem + C_OFF);   // stride 40
  bf16* s_k  = (bf16*)(smem + D_OFF);   // stride 40
  bf16* s_vt = (bf16*)(smem + E_OFF);   // stride 72
  bf16* s_p  = (bf16*)(smem + F_OFF);   // stride 72
  bf16* s_h  = (bf16*)(smem + B_OFF);   // stride 200 (fc1 out, spans B..E)
  bf16* s_at = (bf16*)(smem + A_OFF);   // stride 68  ([c][token], fc2 out)

  const bf16* wq  = wbf + WQ_OFF;
  const bf16* wpj = wbf + WPJ_OFF;
  const bf16* wf1 = wbf + WF1_OFF;
  const bf16* wf2 = wbf + WF2_OFF;

  const int tid  = threadIdx.x;
  const int wid  = tid >> 6;
  const int lane = tid & 63;
  const int quad = lane >> 4;
  const int l15  = lane & 15;
  const int m0   = wid * 16;       // wave's m-tile rows [m0, m0+16)
  const int row0 = m0 + quad * 4;  // C/D frag rows row0..row0+3

  const int blk = blockIdx.x;
  const int b  = blk >> 10;
  const int wh = (blk >> 5) & 31;
  const int ww = blk & 31;
  const size_t base = ((size_t)b * 96) * 65536 + (size_t)wh * 2048 + (size_t)ww * 8;
  // element (c, i, j) of this window at base + c*65536 + i*256 + j ; token = i*8+j

  // ---------------- load x window (float4), keep in regs for residual ----
  float4 xsave[6];
  #pragma unroll
  for (int it = 0; it < 6; it++){
    const int idx4 = it*256 + tid;
    const int c = idx4 >> 4, r = idx4 & 15;
    const int irow = r >> 1, j0 = (r & 1) * 4;
    const int t0 = irow*8 + j0;
    const float4 xv = *(const float4*)(x + base + (size_t)c*65536 + irow*256 + j0);
    xsave[it] = xv;
    s_a[(t0+0)*104 + c] = f2b(xv.x);
    s_a[(t0+1)*104 + c] = f2b(xv.y);
    s_a[(t0+2)*104 + c] = f2b(xv.z);
    s_a[(t0+3)*104 + c] = f2b(xv.w);
  }
  __syncthreads();

  // ---------------- LN helper: 4 threads per row, shuffle combine (params fp32) ----
  auto layernorm = [&](bf16* buf, const float* g, const float* bta){
    const int r = tid >> 2, s = tid & 3;
    bf16* row = buf + r*104;
    const int cb = s*24;
    float vals[24];
    float sum = 0.f, sq = 0.f;
    #pragma unroll
    for (int u = 0; u < 3; u++){
      short8 v8 = *(const short8*)(row + cb + u*8);
      #pragma unroll
      for (int j = 0; j < 8; j++){ float f = s2f(v8[j]); vals[u*8+j] = f; sum += f; sq += f*f; }
    }
    sum += __shfl_xor(sum, 1); sum += __shfl_xor(sum, 2);
    sq  += __shfl_xor(sq , 1); sq  += __shfl_xor(sq , 2);
    const float mu  = sum * (1.f/96.f);
    const float inv = rsqrtf(fmaxf(sq*(1.f/96.f) - mu*mu, 0.f) + EPS);
    #pragma unroll
    for (int u = 0; u < 3; u++){
      const float4 g4a = *(const float4*)(g   + cb + u*8);
      const float4 g4b = *(const float4*)(g   + cb + u*8 + 4);
      const float4 b4a = *(const float4*)(bta + cb + u*8);
      const float4 b4b = *(const float4*)(bta + cb + u*8 + 4);
      short8 o8;
      o8[0] = f2s((vals[u*8+0] - mu) * inv * g4a.x + b4a.x);
      o8[1] = f2s((vals[u*8+1] - mu) * inv * g4a.y + b4a.y);
      o8[2] = f2s((vals[u*8+2] - mu) * inv * g4a.z + b4a.z);
      o8[3] = f2s((vals[u*8+3] - mu) * inv * g4a.w + b4a.w);
      o8[4] = f2s((vals[u*8+4] - mu) * inv * g4b.x + b4b.x);
      o8[5] = f2s((vals[u*8+5] - mu) * inv * g4b.y + b4b.y);
      o8[6] = f2s((vals[u*8+6] - mu) * inv * g4b.z + b4b.z);
      o8[7] = f2s((vals[u*8+7] - mu) * inv * g4b.w + b4b.w);
      *(short8*)(row + cb + u*8) = o8;
    }
  };

  layernorm(s_a, n1g, n1b);
  __syncthreads();

  const f32x4 zac = {0.f, 0.f, 0.f, 0.f};

  // A-fragments of LN1(x): head-invariant, hoisted out of the head loop
  const short8 a0 = *(const short8*)(s_a + (m0+l15)*104 +  0 + quad*8);
  const short8 a1 = *(const short8*)(s_a + (m0+l15)*104 + 32 + quad*8);
  const short8 a2 = *(const short8*)(s_a + (m0+l15)*104 + 64 + quad*8);

  // ---------------- attention: head at a time ----
  for (int h = 0; h < 3; h++){
    // ---- qkv_h : M=64 (wave m-tile), N=96 (q|k|v x 32), K=96
    {
      #pragma unroll
      for (int nt = 0; nt < 6; nt++){
        const int sect = nt >> 1;                 // 0=q 1=k 2=v
        const int d = (nt & 1)*16 + l15;          // 0..31 within head
        const int wrow = sect*96 + h*32 + d;      // row of qkv_w (288x96)
        f32x4 acc = zac;
        if constexpr (PRE){
          const bf16* wp = wq + wrow*96 + quad*8;
          acc = MFMA16(a0, *(const short8*)(wp     ), acc);
          acc = MFMA16(a1, *(const short8*)(wp + 32), acc);
          acc = MFMA16(a2, *(const short8*)(wp + 64), acc);
        } else {
          const float* wp = qkvw + wrow*96 + quad*8;
          acc = MFMA16(a0, ldw8(wp +  0), acc);
          acc = MFMA16(a1, ldw8(wp + 32), acc);
          acc = MFMA16(a2, ldw8(wp + 64), acc);
        }
        const float bias = qkvb[wrow];
        if (sect == 0){
          #pragma unroll
          for (int r = 0; r < 4; r++)
            s_q[(row0+r)*40 + d] = f2b((acc[r] + bias) * QSC);
        } else if (sect == 1){
          #pragma unroll
          for (int r = 0; r < 4; r++)
            s_k[(row0+r)*40 + d] = f2b(acc[r] + bias);
        } else {
          short4v pk;
          #pragma unroll
          for (int r = 0; r < 4; r++) pk[r] = f2s(acc[r] + bias);
          *(short4v*)(s_vt + d*72 + row0) = pk;   // V^T, 4 consecutive tokens
        }
      }
    }
    __syncthreads();

    // ---- scores S = q k^T (+rpb bias), register softmax -> P ----
    {
      float bv[4][4];
      if constexpr (PRE){
        // dense precomputed bias [h][row][col]: coalesced 64B per 16-lane group
        #pragma unroll
        for (int nt = 0; nt < 4; nt++)
          #pragma unroll
          for (int r = 0; r < 4; r++)
            bv[nt][r] = btab[(h*64 + row0 + r)*64 + nt*16 + l15];
      }
      const short8 aq = *(const short8*)(s_q + (m0+l15)*40 + quad*8);
      f32x4 sc[4];
      #pragma unroll
      for (int nt = 0; nt < 4; nt++){
        const short8 bk = *(const short8*)(s_k + (nt*16+l15)*40 + quad*8);
        sc[nt] = MFMA16(aq, bk, zac);
      }
      if constexpr (PRE){
        #pragma unroll
        for (int nt = 0; nt < 4; nt++)
          #pragma unroll
          for (int r = 0; r < 4; r++)
            sc[nt][r] += bv[nt][r];
      } else {
        #pragma unroll
        for (int nt = 0; nt < 4; nt++){
          const int col = nt*16 + l15, ci = col >> 3, cj = col & 7;
          #pragma unroll
          for (int r = 0; r < 4; r++){
            const int row = row0 + r, ri = row >> 3, rj = row & 7;
            const int rel = (ri - ci + 7)*15 + (rj - cj + 7);
            sc[nt][r] += rpb[rel*3 + h];
          }
        }
      }
      #pragma unroll
      for (int r = 0; r < 4; r++){
        float mx = fmaxf(fmaxf(sc[0][r], sc[1][r]), fmaxf(sc[2][r], sc[3][r]));
        mx = fmaxf(mx, __shfl_xor(mx, 1));
        mx = fmaxf(mx, __shfl_xor(mx, 2));
        mx = fmaxf(mx, __shfl_xor(mx, 4));
        mx = fmaxf(mx, __shfl_xor(mx, 8));
        const float e0 = __expf(sc[0][r]-mx), e1 = __expf(sc[1][r]-mx);
        const float e2 = __expf(sc[2][r]-mx), e3 = __expf(sc[3][r]-mx);
        float sm = e0+e1+e2+e3;
        sm += __shfl_xor(sm, 1);
        sm += __shfl_xor(sm, 2);
        sm += __shfl_xor(sm, 4);
        sm += __shfl_xor(sm, 8);
        const float rs = 1.f / sm;
        const int prow = (row0 + r)*72;
        s_p[prow +  0 + l15] = f2b(e0*rs);
        s_p[prow + 16 + l15] = f2b(e1*rs);
        s_p[prow + 32 + l15] = f2b(e2*rs);
        s_p[prow + 48 + l15] = f2b(e3*rs);
      }
    }
    __syncthreads();

    // ---- PV : M=64, N=32, K=64 -> ao[:, h*32 + d] ----
    {
      const short8 p0 = *(const short8*)(s_p + (m0+l15)*72 +  0 + quad*8);
      const short8 p1 = *(const short8*)(s_p + (m0+l15)*72 + 32 + quad*8);
      #pragma unroll
      for (int nt = 0; nt < 2; nt++){
        f32x4 acc = zac;
        acc = MFMA16(p0, *(const short8*)(s_vt + (nt*16+l15)*72 +  0 + quad*8), acc);
        acc = MFMA16(p1, *(const short8*)(s_vt + (nt*16+l15)*72 + 32 + quad*8), acc);
        #pragma unroll
        for (int r = 0; r < 4; r++)
          s_ao[(row0+r)*104 + h*32 + nt*16 + l15] = f2b(acc[r]);
      }
    }
    __syncthreads();
  }

  // ---------------- proj: M=64, N=96, K=96 (A=s_ao -> s_a) ----
  {
    const short8 b0 = *(const short8*)(s_ao + (m0+l15)*104 +  0 + quad*8);
    const short8 b1 = *(const short8*)(s_ao + (m0+l15)*104 + 32 + quad*8);
    const short8 b2 = *(const short8*)(s_ao + (m0+l15)*104 + 64 + quad*8);
    #pragma unroll
    for (int nt = 0; nt < 6; nt++){
      const int wrow = nt*16 + l15;
      f32x4 acc = zac;
      if constexpr (PRE){
        const bf16* wp = wpj + wrow*96 + quad*8;
        acc = MFMA16(b0, *(const short8*)(wp     ), acc);
        acc = MFMA16(b1, *(const short8*)(wp + 32), acc);
        acc = MFMA16(b2, *(const short8*)(wp + 64), acc);
      } else {
        const float* wp = projw + wrow*96 + quad*8;
        acc = MFMA16(b0, ldw8(wp +  0), acc);
        acc = MFMA16(b1, ldw8(wp + 32), acc);
        acc = MFMA16(b2, ldw8(wp + 64), acc);
      }
      const float bias = projb[wrow];
      #pragma unroll
      for (int r = 0; r < 4; r++)
        s_a[(row0+r)*104 + wrow] = f2b(acc[r] + bias);
    }
  }
  __syncthreads();

  // ---------------- LN2 in place on s_a ----
  layernorm(s_a, n2g, n2b);
  __syncthreads();

  // ---------------- fc1 + GELU: M=64, N=192, K=96 -> s_h[64][200] ----
  {
    const short8 c0 = *(const short8*)(s_a + (m0+l15)*104 +  0 + quad*8);
    const short8 c1 = *(const short8*)(s_a + (m0+l15)*104 + 32 + quad*8);
    const short8 c2 = *(const short8*)(s_a + (m0+l15)*104 + 64 + quad*8);
    #pragma unroll
    for (int nt = 0; nt < 12; nt++){
      const int wrow = nt*16 + l15;
      f32x4 acc = zac;
      if constexpr (PRE){
        const bf16* wp = wf1 + wrow*96 + quad*8;
        acc = MFMA16(c0, *(const short8*)(wp     ), acc);
        acc = MFMA16(c1, *(const short8*)(wp + 32), acc);
        acc = MFMA16(c2, *(const short8*)(wp + 64), acc);
      } else {
        const float* wp = fc1w + wrow*96 + quad*8;
        acc = MFMA16(c0, ldw8(wp +  0), acc);
        acc = MFMA16(c1, ldw8(wp + 32), acc);
        acc = MFMA16(c2, ldw8(wp + 64), acc);
      }
      const float bias = fc1b[wrow];
      #pragma unroll
      for (int r = 0; r < 4; r++){
        const float v = acc[r] + bias;
        // GELU via tanh identity: g = v - v/(e^{2y}+1), y = 0.7978845608*(v+0.044715 v^3)
        const float t = __expf(1.5957691216057308f * (v + 0.044715f*v*v*v));
        const float g = v - v * (1.f / (t + 1.f));
        s_h[(row0+r)*200 + wrow] = f2b(g);
      }
    }
  }
  __syncthreads();

  // ---------------- fc2: M=64, N=96, K=192 -> s_at transposed [96][68] ----
  {
    short8 a[6];
    #pragma unroll
    for (int ks = 0; ks < 6; ks++)
      a[ks] = *(const short8*)(s_h + (m0+l15)*200 + ks*32 + quad*8);
    #pragma unroll
    for (int nt = 0; nt < 6; nt++){
      const int wrow = nt*16 + l15;
      f32x4 acc = zac;
      if constexpr (PRE){
        const bf16* wp = wf2 + wrow*192 + quad*8;
        #pragma unroll
        for (int ks = 0; ks < 6; ks++)
          acc = MFMA16(a[ks], *(const short8*)(wp + ks*32), acc);
      } else {
        const float* wp = fc2w + wrow*192 + quad*8;
        #pragma unroll
        for (int ks = 0; ks < 6; ks++)
          acc = MFMA16(a[ks], ldw8(wp + ks*32), acc);
      }
      const float bias = fc2b[wrow];
      short4v pk;
      #pragma unroll
      for (int r = 0; r < 4; r++) pk[r] = f2s(acc[r] + bias);
      *(short4v*)(s_at + wrow*68 + row0) = pk;   // [c][token], 4 consecutive tokens
    }
  }
  __syncthreads();

  // ---------------- writeout: fp32 residual add from registers, window merge ----
  #pragma unroll
  for (int it = 0; it < 6; it++){
    const int idx4 = it*256 + tid;
    const int c = idx4 >> 4, r = idx4 & 15;
    const int irow = r >> 1, j0 = (r & 1) * 4;
    const int t0 = irow*8 + j0;
    const short4v pv = *(const short4v*)(s_at + c*68 + t0);
    const size_t g = base + (size_t)c*65536 + irow*256 + j0;
    const float4 xv = xsave[it];
    float4 ov;
    ov.x = xv.x + s2f(pv[0]);
    ov.y = xv.y + s2f(pv[1]);
    ov.z = xv.z + s2f(pv[2]);
    ov.w = xv.w + s2f(pv[3]);
    *(float4*)(out + g) = ov;
  }
}

extern "C" void kernel_launch(void* const* d_in, const int* in_sizes, int n_in,
                              void* d_out, int out_size, void* d_ws, size_t ws_size,
                              hipStream_t stream) {
  const float* x     = (const float*)d_in[0];
  const float* qkvw  = (const float*)d_in[1];
  const float* qkvb  = (const float*)d_in[2];
  const float* projw = (const float*)d_in[3];
  const float* projb = (const float*)d_in[4];
  const float* rpb   = (const float*)d_in[5];
  const float* n1g   = (const float*)d_in[6];
  const float* n1b   = (const float*)d_in[7];
  const float* n2g   = (const float*)d_in[8];
  const float* n2b   = (const float*)d_in[9];
  const float* fc1w  = (const float*)d_in[10];
  const float* fc1b  = (const float*)d_in[11];
  const float* fc2w  = (const float*)d_in[12];
  const float* fc2b  = (const float*)d_in[13];
  float* out = (float*)d_out;

  if (ws_size >= WS_NEEDED && d_ws != nullptr) {
    bf16*  wbf  = (bf16*)d_ws;
    float* btab = (float*)((char*)d_ws + BTAB_BYTE_OFF);
    init_ws_kernel<<<dim3(288), dim3(256), 0, stream>>>(
        qkvw, projw, fc1w, fc2w, rpb, wbf, btab);
    swin_block_kernel<true><<<dim3(8192), dim3(TPB), 0, stream>>>(
        x, qkvw, qkvb, projw, projb, rpb,
        n1g, n1b, n2g, n2b, fc1w, fc1b, fc2w, fc2b, out, wbf, btab);
  } else {
    swin_block_kernel<false><<<dim3(8192), dim3(TPB), 0, stream>>>(
        x, qkvw, qkvb, projw, projb, rpb,
        n1g, n1b, n2g, n2b, fc1w, fc1b, fc2w, fc2b, out,
        (const bf16*)nullptr, (const float*)nullptr);
  }
}

// Round 2
// 781.761 us; speedup vs baseline: 1.9627x; 1.0019x over previous
//
#include <hip/hip_runtime.h>
#include <hip/hip_bf16.h>

using bf16 = __hip_bfloat16;
typedef short short8  __attribute__((ext_vector_type(8)));   // 8 bf16 (4 VGPRs) MFMA frag
typedef short short4v __attribute__((ext_vector_type(4)));
typedef float f32x4   __attribute__((ext_vector_type(4)));   // MFMA accumulator

static __device__ __forceinline__ float b2f(bf16 v){ return __bfloat162float(v); }
static __device__ __forceinline__ bf16  f2b(float v){ return __float2bfloat16(v); }
static __device__ __forceinline__ float s2f(short s){ return __bfloat162float(__builtin_bit_cast(bf16, s)); }
static __device__ __forceinline__ short f2s(float f){ return __builtin_bit_cast(short, __float2bfloat16(f)); }

// fallback path: load 8 consecutive fp32 weights -> bf16x8 MFMA fragment
static __device__ __forceinline__ short8 ldw8(const float* __restrict__ p){
  const float4 u = *(const float4*)(p);
  const float4 v = *(const float4*)(p + 4);
  short8 r;
  r[0]=f2s(u.x); r[1]=f2s(u.y); r[2]=f2s(u.z); r[3]=f2s(u.w);
  r[4]=f2s(v.x); r[5]=f2s(v.y); r[6]=f2s(v.z); r[7]=f2s(v.w);
  return r;
}

#define MFMA16(a,b,c) __builtin_amdgcn_mfma_f32_16x16x32_bf16((a),(b),(c),0,0,0)

constexpr int TPB = 256;
constexpr float EPS = 1e-5f;
constexpr float QSC = 0.17677669529663687f;   // 32^-0.5

// ---- d_ws layout: pre-converted bf16 weights + dense rel-pos bias table
constexpr int WQ_OFF  = 0;        // qkvw  288x96 bf16
constexpr int WPJ_OFF = 27648;    // projw  96x96
constexpr int WF1_OFF = 36864;    // fc1w  192x96
constexpr int WF2_OFF = 55296;    // fc2w  96x192
constexpr int WTOT    = 73728;    // total bf16 weight elements
constexpr int BTAB_BYTE_OFF = 147456;          // fp32 [3][64][64]
constexpr size_t WS_NEEDED = 147456 + 49152;   // 196,608 B

// ---- LDS regions (byte offsets). Time-shared:
//  R0 (13312): s_a [64][104] (x/LN1)  ->  q[64][40]+k[64][40]  ->  proj-out/LN2 [64][104]  ->  s_at [96][68]
//  R1 (13312): s_ao [64][104] (attn out)  ->  low half of s_h
//  R2 (13824): vt [32][72] + p [64][72]   ->  high half of s_h
//  s_h [64][200] (fc1 out) spans R1+R2 (25600 <= 27136)
constexpr int R0_OFF = 0;
constexpr int R1_OFF = 13312;
constexpr int R2_OFF = 26624;
constexpr int SMEM_BYTES = 40448;   // *4 = 161,792 <= 163,840 -> 4 blocks/CU (16 waves)

__global__ void init_ws_kernel(
    const float* __restrict__ qkvw, const float* __restrict__ projw,
    const float* __restrict__ fc1w, const float* __restrict__ fc2w,
    const float* __restrict__ rpb,
    bf16* __restrict__ wbf, float* __restrict__ btab)
{
  const int i = blockIdx.x * 256 + threadIdx.x;
  if (i < WTOT){
    float v;
    if (i < WPJ_OFF)      v = qkvw[i];
    else if (i < WF1_OFF) v = projw[i - WPJ_OFF];
    else if (i < WF2_OFF) v = fc1w[i - WF1_OFF];
    else                  v = fc2w[i - WF2_OFF];
    wbf[i] = f2b(v);
  }
  if (i < 3*64*64){
    const int h   = i >> 12;
    const int row = (i >> 6) & 63;
    const int col = i & 63;
    const int rel = ((row>>3) - (col>>3) + 7)*15 + ((row&7) - (col&7) + 7);
    btab[i] = rpb[rel*3 + h];
  }
}

template<bool PRE>
__global__ __launch_bounds__(TPB, 4) void swin_block_kernel(
    const float* __restrict__ x,
    const float* __restrict__ qkvw,  const float* __restrict__ qkvb,
    const float* __restrict__ projw, const float* __restrict__ projb,
    const float* __restrict__ rpb,
    const float* __restrict__ n1g,   const float* __restrict__ n1b,
    const float* __restrict__ n2g,   const float* __restrict__ n2b,
    const float* __restrict__ fc1w,  const float* __restrict__ fc1b,
    const float* __restrict__ fc2w,  const float* __restrict__ fc2b,
    float* __restrict__ out,
    const bf16* __restrict__ wbf,    const float* __restrict__ btab)
{
  __shared__ alignas(16) unsigned char smem[SMEM_BYTES];
  bf16* s_a  = (bf16*)(smem + R0_OFF);          // stride 104 (x/LN1; later proj/LN2)
  bf16* s_q  = (bf16*)(smem + R0_OFF);          // stride 40  (overlays s_a after frag hoist)
  bf16* s_k  = (bf16*)(smem + R0_OFF + 5120);   // stride 40
  bf16* s_at = (bf16*)(smem + R0_OFF);          // stride 68  ([c][token], fc2 out)
  bf16* s_ao = (bf16*)(smem + R1_OFF);          // stride 104 (attn out; wave-private rows)
  bf16* s_h  = (bf16*)(smem + R1_OFF);          // stride 200 (fc1 out, spans R1+R2)
  bf16* s_vt = (bf16*)(smem + R2_OFF);          // stride 72  (V^T: [d][token])
  bf16* s_p  = (bf16*)(smem + R2_OFF + 4608);   // stride 72  (wave-private rows)

  const bf16* wq  = wbf + WQ_OFF;
  const bf16* wpj = wbf + WPJ_OFF;
  const bf16* wf1 = wbf + WF1_OFF;
  const bf16* wf2 = wbf + WF2_OFF;

  const int tid  = threadIdx.x;
  const int wid  = tid >> 6;
  const int lane = tid & 63;
  const int quad = lane >> 4;
  const int l15  = lane & 15;
  const int m0   = wid * 16;       // wave's m-tile rows [m0, m0+16)
  const int row0 = m0 + quad * 4;  // C/D frag rows row0..row0+3

  const int blk = blockIdx.x;
  const int b  = blk >> 10;
  const int wh = (blk >> 5) & 31;
  const int ww = blk & 31;
  const size_t base = ((size_t)b * 96) * 65536 + (size_t)wh * 2048 + (size_t)ww * 8;
  // element (c, i, j) of this window at base + c*65536 + i*256 + j ; token = i*8+j

  // ---------------- load x window (float4), keep in regs for residual ----
  float4 xsave[6];
  #pragma unroll
  for (int it = 0; it < 6; it++){
    const int idx4 = it*256 + tid;
    const int c = idx4 >> 4, r = idx4 & 15;
    const int irow = r >> 1, j0 = (r & 1) * 4;
    const int t0 = irow*8 + j0;
    const float4 xv = *(const float4*)(x + base + (size_t)c*65536 + irow*256 + j0);
    xsave[it] = xv;
    s_a[(t0+0)*104 + c] = f2b(xv.x);
    s_a[(t0+1)*104 + c] = f2b(xv.y);
    s_a[(t0+2)*104 + c] = f2b(xv.z);
    s_a[(t0+3)*104 + c] = f2b(xv.w);
  }
  __syncthreads();

  // ---------------- LN helper: 4 threads per row (wave-private rows), shuffle combine ----
  auto layernorm = [&](bf16* buf, const float* g, const float* bta){
    const int r = tid >> 2, s = tid & 3;     // wave w handles rows [16w,16w+16) = own m-tile
    bf16* row = buf + r*104;
    const int cb = s*24;
    float vals[24];
    float sum = 0.f, sq = 0.f;
    #pragma unroll
    for (int u = 0; u < 3; u++){
      short8 v8 = *(const short8*)(row + cb + u*8);
      #pragma unroll
      for (int j = 0; j < 8; j++){ float f = s2f(v8[j]); vals[u*8+j] = f; sum += f; sq += f*f; }
    }
    sum += __shfl_xor(sum, 1); sum += __shfl_xor(sum, 2);
    sq  += __shfl_xor(sq , 1); sq  += __shfl_xor(sq , 2);
    const float mu  = sum * (1.f/96.f);
    const float inv = rsqrtf(fmaxf(sq*(1.f/96.f) - mu*mu, 0.f) + EPS);
    #pragma unroll
    for (int u = 0; u < 3; u++){
      const float4 g4a = *(const float4*)(g   + cb + u*8);
      const float4 g4b = *(const float4*)(g   + cb + u*8 + 4);
      const float4 b4a = *(const float4*)(bta + cb + u*8);
      const float4 b4b = *(const float4*)(bta + cb + u*8 + 4);
      short8 o8;
      o8[0] = f2s((vals[u*8+0] - mu) * inv * g4a.x + b4a.x);
      o8[1] = f2s((vals[u*8+1] - mu) * inv * g4a.y + b4a.y);
      o8[2] = f2s((vals[u*8+2] - mu) * inv * g4a.z + b4a.z);
      o8[3] = f2s((vals[u*8+3] - mu) * inv * g4a.w + b4a.w);
      o8[4] = f2s((vals[u*8+4] - mu) * inv * g4b.x + b4b.x);
      o8[5] = f2s((vals[u*8+5] - mu) * inv * g4b.y + b4b.y);
      o8[6] = f2s((vals[u*8+6] - mu) * inv * g4b.z + b4b.z);
      o8[7] = f2s((vals[u*8+7] - mu) * inv * g4b.w + b4b.w);
      *(short8*)(row + cb + u*8) = o8;
    }
  };

  layernorm(s_a, n1g, n1b);   // writes own m-tile rows (no barrier needed before hoist)

  const f32x4 zac = {0.f, 0.f, 0.f, 0.f};

  // A-fragments of LN1(x): own-wave rows, hoisted; s_a dead afterwards
  const short8 a0 = *(const short8*)(s_a + (m0+l15)*104 +  0 + quad*8);
  const short8 a1 = *(const short8*)(s_a + (m0+l15)*104 + 32 + quad*8);
  const short8 a2 = *(const short8*)(s_a + (m0+l15)*104 + 64 + quad*8);
  __syncthreads();   // all waves hoisted before q/k overwrite R0

  // ---------------- attention: head at a time; 2 barriers/head ----
  for (int h = 0; h < 3; h++){
    // ---- qkv_h : M=64 (wave m-tile), N=96 (q|k|v x 32), K=96
    {
      #pragma unroll
      for (int nt = 0; nt < 6; nt++){
        const int sect = nt >> 1;                 // 0=q 1=k 2=v
        const int d = (nt & 1)*16 + l15;          // 0..31 within head
        const int wrow = sect*96 + h*32 + d;      // row of qkv_w (288x96)
        f32x4 acc = zac;
        if constexpr (PRE){
          const bf16* wp = wq + wrow*96 + quad*8;
          acc = MFMA16(a0, *(const short8*)(wp     ), acc);
          acc = MFMA16(a1, *(const short8*)(wp + 32), acc);
          acc = MFMA16(a2, *(const short8*)(wp + 64), acc);
        } else {
          const float* wp = qkvw + wrow*96 + quad*8;
          acc = MFMA16(a0, ldw8(wp +  0), acc);
          acc = MFMA16(a1, ldw8(wp + 32), acc);
          acc = MFMA16(a2, ldw8(wp + 64), acc);
        }
        const float bias = qkvb[wrow];
        if (sect == 0){
          #pragma unroll
          for (int r = 0; r < 4; r++)
            s_q[(row0+r)*40 + d] = f2b((acc[r] + bias) * QSC);
        } else if (sect == 1){
          #pragma unroll
          for (int r = 0; r < 4; r++)
            s_k[(row0+r)*40 + d] = f2b(acc[r] + bias);
        } else {
          short4v pk;
          #pragma unroll
          for (int r = 0; r < 4; r++) pk[r] = f2s(acc[r] + bias);
          *(short4v*)(s_vt + d*72 + row0) = pk;   // V^T, 4 consecutive tokens
        }
      }
    }
    __syncthreads();   // k (cross-wave) and vt (cross-wave) ready

    // ---- scores S = q k^T (+bias), register softmax -> P (wave-private) -> PV, fused ----
    {
      float bv[4][4];
      if constexpr (PRE){
        #pragma unroll
        for (int nt = 0; nt < 4; nt++)
          #pragma unroll
          for (int r = 0; r < 4; r++)
            bv[nt][r] = btab[(h*64 + row0 + r)*64 + nt*16 + l15];
      }
      const short8 aq = *(const short8*)(s_q + (m0+l15)*40 + quad*8);  // own-wave rows
      f32x4 sc[4];
      #pragma unroll
      for (int nt = 0; nt < 4; nt++){
        const short8 bk = *(const short8*)(s_k + (nt*16+l15)*40 + quad*8);
        sc[nt] = MFMA16(aq, bk, zac);
      }
      if constexpr (PRE){
        #pragma unroll
        for (int nt = 0; nt < 4; nt++)
          #pragma unroll
          for (int r = 0; r < 4; r++)
            sc[nt][r] += bv[nt][r];
      } else {
        #pragma unroll
        for (int nt = 0; nt < 4; nt++){
          const int col = nt*16 + l15, ci = col >> 3, cj = col & 7;
          #pragma unroll
          for (int r = 0; r < 4; r++){
            const int row = row0 + r, ri = row >> 3, rj = row & 7;
            const int rel = (ri - ci + 7)*15 + (rj - cj + 7);
            sc[nt][r] += rpb[rel*3 + h];
          }
        }
      }
      #pragma unroll
      for (int r = 0; r < 4; r++){
        float mx = fmaxf(fmaxf(sc[0][r], sc[1][r]), fmaxf(sc[2][r], sc[3][r]));
        mx = fmaxf(mx, __shfl_xor(mx, 1));
        mx = fmaxf(mx, __shfl_xor(mx, 2));
        mx = fmaxf(mx, __shfl_xor(mx, 4));
        mx = fmaxf(mx, __shfl_xor(mx, 8));
        const float e0 = __expf(sc[0][r]-mx), e1 = __expf(sc[1][r]-mx);
        const float e2 = __expf(sc[2][r]-mx), e3 = __expf(sc[3][r]-mx);
        float sm = e0+e1+e2+e3;
        sm += __shfl_xor(sm, 1);
        sm += __shfl_xor(sm, 2);
        sm += __shfl_xor(sm, 4);
        sm += __shfl_xor(sm, 8);
        const float rs = 1.f / sm;
        const int prow = (row0 + r)*72;
        s_p[prow +  0 + l15] = f2b(e0*rs);
        s_p[prow + 16 + l15] = f2b(e1*rs);
        s_p[prow + 32 + l15] = f2b(e2*rs);
        s_p[prow + 48 + l15] = f2b(e3*rs);
      }

      // ---- PV : M=64, N=32, K=64 -> ao[:, h*32 + d] (p own-wave rows; vt barrier-protected)
      const short8 p0 = *(const short8*)(s_p + (m0+l15)*72 +  0 + quad*8);
      const short8 p1 = *(const short8*)(s_p + (m0+l15)*72 + 32 + quad*8);
      #pragma unroll
      for (int nt = 0; nt < 2; nt++){
        f32x4 acc = zac;
        acc = MFMA16(p0, *(const short8*)(s_vt + (nt*16+l15)*72 +  0 + quad*8), acc);
        acc = MFMA16(p1, *(const short8*)(s_vt + (nt*16+l15)*72 + 32 + quad*8), acc);
        #pragma unroll
        for (int r = 0; r < 4; r++)
          s_ao[(row0+r)*104 + h*32 + nt*16 + l15] = f2b(acc[r]);
      }
    }
    __syncthreads();   // protect q/k/vt overwrite (next head) / R0 overwrite (proj)
  }

  // ---------------- proj: M=64, N=96, K=96 (A=s_ao own-wave rows -> s_a) ----
  {
    const short8 b0 = *(const short8*)(s_ao + (m0+l15)*104 +  0 + quad*8);
    const short8 b1 = *(const short8*)(s_ao + (m0+l15)*104 + 32 + quad*8);
    const short8 b2 = *(const short8*)(s_ao + (m0+l15)*104 + 64 + quad*8);
    #pragma unroll
    for (int nt = 0; nt < 6; nt++){
      const int wrow = nt*16 + l15;
      f32x4 acc = zac;
      if constexpr (PRE){
        const bf16* wp = wpj + wrow*96 + quad*8;
        acc = MFMA16(b0, *(const short8*)(wp     ), acc);
        acc = MFMA16(b1, *(const short8*)(wp + 32), acc);
        acc = MFMA16(b2, *(const short8*)(wp + 64), acc);
      } else {
        const float* wp = projw + wrow*96 + quad*8;
        acc = MFMA16(b0, ldw8(wp +  0), acc);
        acc = MFMA16(b1, ldw8(wp + 32), acc);
        acc = MFMA16(b2, ldw8(wp + 64), acc);
      }
      const float bias = projb[wrow];
      #pragma unroll
      for (int r = 0; r < 4; r++)
        s_a[(row0+r)*104 + wrow] = f2b(acc[r] + bias);   // own-wave rows
    }
  }
  __syncthreads();   // all waves done with s_ao reads + vt/p reads before h overwrites R1/R2

  // ---------------- LN2 in place on s_a (own-wave rows; no barrier needed after) ----
  layernorm(s_a, n2g, n2b);

  // ---------------- fc1 + GELU: M=64, N=192, K=96 -> s_h[64][200] (own-wave rows) ----
  {
    const short8 c0 = *(const short8*)(s_a + (m0+l15)*104 +  0 + quad*8);
    const short8 c1 = *(const short8*)(s_a + (m0+l15)*104 + 32 + quad*8);
    const short8 c2 = *(const short8*)(s_a + (m0+l15)*104 + 64 + quad*8);
    #pragma unroll
    for (int nt = 0; nt < 12; nt++){
      const int wrow = nt*16 + l15;
      f32x4 acc = zac;
      if constexpr (PRE){
        const bf16* wp = wf1 + wrow*96 + quad*8;
        acc = MFMA16(c0, *(const short8*)(wp     ), acc);
        acc = MFMA16(c1, *(const short8*)(wp + 32), acc);
        acc = MFMA16(c2, *(const short8*)(wp + 64), acc);
      } else {
        const float* wp = fc1w + wrow*96 + quad*8;
        acc = MFMA16(c0, ldw8(wp +  0), acc);
        acc = MFMA16(c1, ldw8(wp + 32), acc);
        acc = MFMA16(c2, ldw8(wp + 64), acc);
      }
      const float bias = fc1b[wrow];
      #pragma unroll
      for (int r = 0; r < 4; r++){
        const float v = acc[r] + bias;
        // GELU via tanh identity: g = v - v/(e^{2y}+1), y = 0.7978845608*(v+0.044715 v^3)
        const float t = __expf(1.5957691216057308f * (v + 0.044715f*v*v*v));
        const float g = v - v * (1.f / (t + 1.f));
        s_h[(row0+r)*200 + wrow] = f2b(g);
      }
    }
  }
  __syncthreads();   // all waves' c-frag hoists done before s_at overwrites R0

  // ---------------- fc2: M=64, N=96, K=192 -> s_at transposed [96][68] ----
  {
    short8 a[6];
    #pragma unroll
    for (int ks = 0; ks < 6; ks++)
      a[ks] = *(const short8*)(s_h + (m0+l15)*200 + ks*32 + quad*8);   // own-wave rows
    #pragma unroll
    for (int nt = 0; nt < 6; nt++){
      const int wrow = nt*16 + l15;
      f32x4 acc = zac;
      if constexpr (PRE){
        const bf16* wp = wf2 + wrow*192 + quad*8;
        #pragma unroll
        for (int ks = 0; ks < 6; ks++)
          acc = MFMA16(a[ks], *(const short8*)(wp + ks*32), acc);
      } else {
        const float* wp = fc2w + wrow*192 + quad*8;
        #pragma unroll
        for (int ks = 0; ks < 6; ks++)
          acc = MFMA16(a[ks], ldw8(wp + ks*32), acc);
      }
      const float bias = fc2b[wrow];
      short4v pk;
      #pragma unroll
      for (int r = 0; r < 4; r++) pk[r] = f2s(acc[r] + bias);
      *(short4v*)(s_at + wrow*68 + row0) = pk;   // [c][token], 4 consecutive tokens
    }
  }
  __syncthreads();

  // ---------------- writeout: fp32 residual add from registers, window merge ----
  #pragma unroll
  for (int it = 0; it < 6; it++){
    const int idx4 = it*256 + tid;
    const int c = idx4 >> 4, r = idx4 & 15;
    const int irow = r >> 1, j0 = (r & 1) * 4;
    const int t0 = irow*8 + j0;
    const short4v pv = *(const short4v*)(s_at + c*68 + t0);
    const size_t g = base + (size_t)c*65536 + irow*256 + j0;
    const float4 xv = xsave[it];
    float4 ov;
    ov.x = xv.x + s2f(pv[0]);
    ov.y = xv.y + s2f(pv[1]);
    ov.z = xv.z + s2f(pv[2]);
    ov.w = xv.w + s2f(pv[3]);
    *(float4*)(out + g) = ov;
  }
}

extern "C" void kernel_launch(void* const* d_in, const int* in_sizes, int n_in,
                              void* d_out, int out_size, void* d_ws, size_t ws_size,
                              hipStream_t stream) {
  const float* x     = (const float*)d_in[0];
  const float* qkvw  = (const float*)d_in[1];
  const float* qkvb  = (const float*)d_in[2];
  const float* projw = (const float*)d_in[3];
  const float* projb = (const float*)d_in[4];
  const float* rpb   = (const float*)d_in[5];
  const float* n1g   = (const float*)d_in[6];
  const float* n1b   = (const float*)d_in[7];
  const float* n2g   = (const float*)d_in[8];
  const float* n2b   = (const float*)d_in[9];
  const float* fc1w  = (const float*)d_in[10];
  const float* fc1b  = (const float*)d_in[11];
  const float* fc2w  = (const float*)d_in[12];
  const float* fc2b  = (const float*)d_in[13];
  float* out = (float*)d_out;

  if (ws_size >= WS_NEEDED && d_ws != nullptr) {
    bf16*  wbf  = (bf16*)d_ws;
    float* btab = (float*)((char*)d_ws + BTAB_BYTE_OFF);
    init_ws_kernel<<<dim3(288), dim3(256), 0, stream>>>(
        qkvw, projw, fc1w, fc2w, rpb, wbf, btab);
    swin_block_kernel<true><<<dim3(8192), dim3(TPB), 0, stream>>>(
        x, qkvw, qkvb, projw, projb, rpb,
        n1g, n1b, n2g, n2b, fc1w, fc1b, fc2w, fc2b, out, wbf, btab);
  } else {
    swin_block_kernel<false><<<dim3(8192), dim3(TPB), 0, stream>>>(
        x, qkvw, qkvb, projw, projb, rpb,
        n1g, n1b, n2g, n2b, fc1w, fc1b, fc2w, fc2b, out,
        (const bf16*)nullptr, (const float*)nullptr);
  }
}

// Round 3
// 617.568 us; speedup vs baseline: 2.4845x; 1.2659x over previous
//
#include <hip/hip_runtime.h>
#include <hip/hip_bf16.h>

using bf16 = __hip_bfloat16;
typedef short short8  __attribute__((ext_vector_type(8)));   // 8 bf16 (4 VGPRs) MFMA frag
typedef short short4v __attribute__((ext_vector_type(4)));
typedef float f32x4   __attribute__((ext_vector_type(4)));   // MFMA accumulator

static __device__ __forceinline__ float b2f(bf16 v){ return __bfloat162float(v); }
static __device__ __forceinline__ bf16  f2b(float v){ return __float2bfloat16(v); }
static __device__ __forceinline__ float s2f(short s){ return __bfloat162float(__builtin_bit_cast(bf16, s)); }
static __device__ __forceinline__ short f2s(float f){ return __builtin_bit_cast(short, __float2bfloat16(f)); }

// fallback path: load 8 consecutive fp32 weights -> bf16x8 MFMA fragment
static __device__ __forceinline__ short8 ldw8(const float* __restrict__ p){
  const float4 u = *(const float4*)(p);
  const float4 v = *(const float4*)(p + 4);
  short8 r;
  r[0]=f2s(u.x); r[1]=f2s(u.y); r[2]=f2s(u.z); r[3]=f2s(u.w);
  r[4]=f2s(v.x); r[5]=f2s(v.y); r[6]=f2s(v.z); r[7]=f2s(v.w);
  return r;
}

#define MFMA16(a,b,c) __builtin_amdgcn_mfma_f32_16x16x32_bf16((a),(b),(c),0,0,0)

constexpr int TPB = 256;
constexpr float EPS = 1e-5f;
constexpr float QSC = 0.17677669529663687f;   // 32^-0.5

// ---- d_ws layout: pre-converted bf16 weights + dense rel-pos bias table
constexpr int WQ_OFF  = 0;        // qkvw  288x96 bf16
constexpr int WPJ_OFF = 27648;    // projw  96x96
constexpr int WF1_OFF = 36864;    // fc1w  192x96
constexpr int WF2_OFF = 55296;    // fc2w  96x192
constexpr int WTOT    = 73728;    // total bf16 weight elements
constexpr int BTAB_BYTE_OFF = 147456;          // fp32 [3][64][64]
constexpr size_t WS_NEEDED = 147456 + 49152;   // 196,608 B

// ---- LDS regions (byte offsets). TWO windows per block (rows 0..63 = win0, 64..127 = win1).
//  R0 (26624): s_a [128][104] (x/LN1) -> q[128][40]+k[128][40] -> proj/LN2 [128][104] -> s_at [96][136]
//  R1 (26624): s_ao [128][104] (attn out) -> low part of s_h
//  R2 (27648): vt [2][32][72] + p [128][72] -> high part of s_h
//  s_h [128][200] (fc1 out) spans R1+R2 (51200 <= 54272)
constexpr int R0_OFF = 0;
constexpr int R1_OFF = 26624;
constexpr int R2_OFF = 53248;
constexpr int SMEM_BYTES = 80896;   // *2 = 161,792 <= 163,840 -> 2 blocks/CU (8 waves)

__global__ void init_ws_kernel(
    const float* __restrict__ qkvw, const float* __restrict__ projw,
    const float* __restrict__ fc1w, const float* __restrict__ fc2w,
    const float* __restrict__ rpb,
    bf16* __restrict__ wbf, float* __restrict__ btab)
{
  const int i = blockIdx.x * 256 + threadIdx.x;
  if (i < WTOT){
    float v;
    if (i < WPJ_OFF)      v = qkvw[i];
    else if (i < WF1_OFF) v = projw[i - WPJ_OFF];
    else if (i < WF2_OFF) v = fc1w[i - WF1_OFF];
    else                  v = fc2w[i - WF2_OFF];
    wbf[i] = f2b(v);
  }
  if (i < 3*64*64){
    const int h   = i >> 12;
    const int row = (i >> 6) & 63;
    const int col = i & 63;
    const int rel = ((row>>3) - (col>>3) + 7)*15 + ((row&7) - (col&7) + 7);
    btab[i] = rpb[rel*3 + h];
  }
}

template<bool PRE>
__global__ __launch_bounds__(TPB, 2) void swin_block_kernel(
    const float* __restrict__ x,
    const float* __restrict__ qkvw,  const float* __restrict__ qkvb,
    const float* __restrict__ projw, const float* __restrict__ projb,
    const float* __restrict__ rpb,
    const float* __restrict__ n1g,   const float* __restrict__ n1b,
    const float* __restrict__ n2g,   const float* __restrict__ n2b,
    const float* __restrict__ fc1w,  const float* __restrict__ fc1b,
    const float* __restrict__ fc2w,  const float* __restrict__ fc2b,
    float* __restrict__ out,
    const bf16* __restrict__ wbf,    const float* __restrict__ btab)
{
  __shared__ alignas(16) unsigned char smem[SMEM_BYTES];
  bf16* s_a  = (bf16*)(smem + R0_OFF);           // [128][104]
  bf16* s_q  = (bf16*)(smem + R0_OFF);           // [128][40] (overlays s_a after frag hoist)
  bf16* s_k  = (bf16*)(smem + R0_OFF + 10240);   // [128][40]
  bf16* s_at = (bf16*)(smem + R0_OFF);           // [96][136] ([c][token], fc2 out)
  bf16* s_ao = (bf16*)(smem + R1_OFF);           // [128][104] (attn out; wave-private rows)
  bf16* s_h  = (bf16*)(smem + R1_OFF);           // [128][200] (fc1 out, spans R1+R2)
  bf16* s_vt = (bf16*)(smem + R2_OFF);           // [2][32][72] (V^T per window)
  bf16* s_p  = (bf16*)(smem + R2_OFF + 9216);    // [128][72] (wave-private rows)

  const bf16* wQ  = wbf + WQ_OFF;
  const bf16* wP  = wbf + WPJ_OFF;
  const bf16* wF1 = wbf + WF1_OFF;
  const bf16* wF2 = wbf + WF2_OFF;

  const int tid  = threadIdx.x;
  const int wid  = tid >> 6;
  const int lane = tid & 63;
  const int quad = lane >> 4;
  const int l15  = lane & 15;
  const int m0   = wid * 16;       // wave's m-tile rows within a window
  const int row0 = m0 + quad * 4;  // C/D frag rows (within window)

  // grid 4096: 8 batch x 32 wh x 16 window-pairs (2 adjacent windows along W)
  const int blk = blockIdx.x;
  const int b    = blk >> 9;
  const int wh   = (blk >> 4) & 31;
  const int wcol = blk & 15;
  const size_t base = ((size_t)b * 96) * 65536 + (size_t)wh * 2048 + (size_t)wcol * 16;
  // element (c, i, j) at base + c*65536 + i*256 + j ; j in [0,16): win = j>>3, token = i*8 + (j&7)

  // ---------------- load x (float4), keep in regs for residual ----
  float4 xsave[12];
  #pragma unroll
  for (int it = 0; it < 12; it++){
    const int idx4 = it*256 + tid;
    const int c = idx4 >> 5, r = idx4 & 31;
    const int irow = r >> 2, j0 = (r & 3) * 4;
    const float4 xv = *(const float4*)(x + base + (size_t)c*65536 + irow*256 + j0);
    xsave[it] = xv;
    const int srow = (j0 >> 3)*64 + irow*8 + (j0 & 7);
    s_a[(srow+0)*104 + c] = f2b(xv.x);
    s_a[(srow+1)*104 + c] = f2b(xv.y);
    s_a[(srow+2)*104 + c] = f2b(xv.z);
    s_a[(srow+3)*104 + c] = f2b(xv.w);
  }
  __syncthreads();

  // ---------------- LN helper: 4 threads/row, 2 windows, wave-private rows ----
  auto layernorm = [&](bf16* buf, const float* g, const float* bta){
    const int rr = tid >> 2, s = tid & 3;
    const int cb = s*24;
    float gv[24], bb[24];
    #pragma unroll
    for (int u = 0; u < 6; u++){
      const float4 g4 = *(const float4*)(g   + cb + u*4);
      const float4 b4 = *(const float4*)(bta + cb + u*4);
      gv[u*4+0]=g4.x; gv[u*4+1]=g4.y; gv[u*4+2]=g4.z; gv[u*4+3]=g4.w;
      bb[u*4+0]=b4.x; bb[u*4+1]=b4.y; bb[u*4+2]=b4.z; bb[u*4+3]=b4.w;
    }
    #pragma unroll
    for (int wv = 0; wv < 2; wv++){
      bf16* row = buf + (wv*64 + rr)*104;
      float vals[24];
      float sum = 0.f, sq = 0.f;
      #pragma unroll
      for (int u = 0; u < 3; u++){
        short8 v8 = *(const short8*)(row + cb + u*8);
        #pragma unroll
        for (int j = 0; j < 8; j++){ float f = s2f(v8[j]); vals[u*8+j] = f; sum += f; sq += f*f; }
      }
      sum += __shfl_xor(sum, 1); sum += __shfl_xor(sum, 2);
      sq  += __shfl_xor(sq , 1); sq  += __shfl_xor(sq , 2);
      const float mu  = sum * (1.f/96.f);
      const float inv = rsqrtf(fmaxf(sq*(1.f/96.f) - mu*mu, 0.f) + EPS);
      #pragma unroll
      for (int u = 0; u < 3; u++){
        short8 o8;
        #pragma unroll
        for (int j = 0; j < 8; j++)
          o8[j] = f2s((vals[u*8+j] - mu) * inv * gv[u*8+j] + bb[u*8+j]);
        *(short8*)(row + cb + u*8) = o8;
      }
    }
  };

  layernorm(s_a, n1g, n1b);   // wave-private rows; no barrier needed before hoist

  const f32x4 zac = {0.f, 0.f, 0.f, 0.f};

  // A-fragments of LN1(x) for both windows (registers; s_a then dead)
  short8 A0[2], A1[2], A2[2];
  #pragma unroll
  for (int wv = 0; wv < 2; wv++){
    const bf16* ap = s_a + (wv*64 + m0 + l15)*104 + quad*8;
    A0[wv] = *(const short8*)(ap);
    A1[wv] = *(const short8*)(ap + 32);
    A2[wv] = *(const short8*)(ap + 64);
  }
  __syncthreads();   // all waves hoisted before q/k overwrite R0

  // ---------------- attention: head at a time; 2 barriers/head; both windows ----
  for (int h = 0; h < 3; h++){
    // ---- qkv_h : per nt, shared W-fragments serve both windows
    #pragma unroll
    for (int nt = 0; nt < 6; nt++){
      const int sect = nt >> 1;                 // 0=q 1=k 2=v
      const int d = (nt & 1)*16 + l15;          // 0..31 within head
      const int wrow = sect*96 + h*32 + d;      // row of qkv_w (288x96)
      short8 w0, w1, w2;
      if constexpr (PRE){
        const bf16* wp = wQ + wrow*96 + quad*8;
        w0 = *(const short8*)(wp);
        w1 = *(const short8*)(wp + 32);
        w2 = *(const short8*)(wp + 64);
      } else {
        const float* wp = qkvw + wrow*96 + quad*8;
        w0 = ldw8(wp); w1 = ldw8(wp + 32); w2 = ldw8(wp + 64);
      }
      const float bias = qkvb[wrow];
      const f32x4 bacc = {bias, bias, bias, bias};
      #pragma unroll
      for (int wv = 0; wv < 2; wv++){
        f32x4 acc = bacc;
        acc = MFMA16(A0[wv], w0, acc);
        acc = MFMA16(A1[wv], w1, acc);
        acc = MFMA16(A2[wv], w2, acc);
        if (sect == 0){
          #pragma unroll
          for (int r = 0; r < 4; r++)
            s_q[(wv*64 + row0 + r)*40 + d] = f2b(acc[r] * QSC);
        } else if (sect == 1){
          #pragma unroll
          for (int r = 0; r < 4; r++)
            s_k[(wv*64 + row0 + r)*40 + d] = f2b(acc[r]);
        } else {
          short4v pk;
          #pragma unroll
          for (int r = 0; r < 4; r++) pk[r] = f2s(acc[r]);
          *(short4v*)(s_vt + wv*2304 + d*72 + row0) = pk;   // V^T, 4 consecutive tokens
        }
      }
    }
    __syncthreads();   // k, vt (cross-wave) ready

    // ---- scores + softmax + PV, fused; bias rows shared across windows ----
    {
      f32x4 bvv[4];
      if constexpr (PRE){
        #pragma unroll
        for (int nt = 0; nt < 4; nt++)
          #pragma unroll
          for (int r = 0; r < 4; r++)
            bvv[nt][r] = btab[(h*64 + row0 + r)*64 + nt*16 + l15];
      } else {
        #pragma unroll
        for (int nt = 0; nt < 4; nt++){
          const int col = nt*16 + l15, ci = col >> 3, cj = col & 7;
          #pragma unroll
          for (int r = 0; r < 4; r++){
            const int row = row0 + r, ri = row >> 3, rj = row & 7;
            const int rel = (ri - ci + 7)*15 + (rj - cj + 7);
            bvv[nt][r] = rpb[rel*3 + h];
          }
        }
      }
      #pragma unroll
      for (int wv = 0; wv < 2; wv++){
        const short8 aq = *(const short8*)(s_q + (wv*64 + m0 + l15)*40 + quad*8);
        f32x4 sc[4];
        #pragma unroll
        for (int nt = 0; nt < 4; nt++){
          const short8 bk = *(const short8*)(s_k + (wv*64 + nt*16 + l15)*40 + quad*8);
          sc[nt] = MFMA16(aq, bk, bvv[nt]);   // bias folded into C-input
        }
        #pragma unroll
        for (int r = 0; r < 4; r++){
          float mx = fmaxf(fmaxf(sc[0][r], sc[1][r]), fmaxf(sc[2][r], sc[3][r]));
          mx = fmaxf(mx, __shfl_xor(mx, 1));
          mx = fmaxf(mx, __shfl_xor(mx, 2));
          mx = fmaxf(mx, __shfl_xor(mx, 4));
          mx = fmaxf(mx, __shfl_xor(mx, 8));
          const float e0 = __expf(sc[0][r]-mx), e1 = __expf(sc[1][r]-mx);
          const float e2 = __expf(sc[2][r]-mx), e3 = __expf(sc[3][r]-mx);
          float sm = e0+e1+e2+e3;
          sm += __shfl_xor(sm, 1);
          sm += __shfl_xor(sm, 2);
          sm += __shfl_xor(sm, 4);
          sm += __shfl_xor(sm, 8);
          const float rs = 1.f / sm;
          const int prow = (wv*64 + row0 + r)*72;
          s_p[prow +  0 + l15] = f2b(e0*rs);
          s_p[prow + 16 + l15] = f2b(e1*rs);
          s_p[prow + 32 + l15] = f2b(e2*rs);
          s_p[prow + 48 + l15] = f2b(e3*rs);
        }

        // PV : p own-wave rows; vt barrier-protected
        const short8 p0 = *(const short8*)(s_p + (wv*64 + m0 + l15)*72 +  0 + quad*8);
        const short8 p1 = *(const short8*)(s_p + (wv*64 + m0 + l15)*72 + 32 + quad*8);
        #pragma unroll
        for (int nt = 0; nt < 2; nt++){
          f32x4 acc = zac;
          acc = MFMA16(p0, *(const short8*)(s_vt + wv*2304 + (nt*16+l15)*72 +  0 + quad*8), acc);
          acc = MFMA16(p1, *(const short8*)(s_vt + wv*2304 + (nt*16+l15)*72 + 32 + quad*8), acc);
          #pragma unroll
          for (int r = 0; r < 4; r++)
            s_ao[(wv*64 + row0 + r)*104 + h*32 + nt*16 + l15] = f2b(acc[r]);
        }
      }
    }
    __syncthreads();   // protect q/k/vt overwrite (next head) / R0 overwrite (proj)
  }

  // ---------------- proj: shared W-frags, both windows -> s_a ----
  {
    short8 B0[2], B1[2], B2[2];
    #pragma unroll
    for (int wv = 0; wv < 2; wv++){
      const bf16* bp = s_ao + (wv*64 + m0 + l15)*104 + quad*8;
      B0[wv] = *(const short8*)(bp);
      B1[wv] = *(const short8*)(bp + 32);
      B2[wv] = *(const short8*)(bp + 64);
    }
    #pragma unroll
    for (int nt = 0; nt < 6; nt++){
      const int wrow = nt*16 + l15;
      short8 w0, w1, w2;
      if constexpr (PRE){
        const bf16* wp = wP + wrow*96 + quad*8;
        w0 = *(const short8*)(wp);
        w1 = *(const short8*)(wp + 32);
        w2 = *(const short8*)(wp + 64);
      } else {
        const float* wp = projw + wrow*96 + quad*8;
        w0 = ldw8(wp); w1 = ldw8(wp + 32); w2 = ldw8(wp + 64);
      }
      const float bias = projb[wrow];
      const f32x4 bacc = {bias, bias, bias, bias};
      #pragma unroll
      for (int wv = 0; wv < 2; wv++){
        f32x4 acc = bacc;
        acc = MFMA16(B0[wv], w0, acc);
        acc = MFMA16(B1[wv], w1, acc);
        acc = MFMA16(B2[wv], w2, acc);
        #pragma unroll
        for (int r = 0; r < 4; r++)
          s_a[(wv*64 + row0 + r)*104 + wrow] = f2b(acc[r]);   // own-wave rows
      }
    }
  }
  __syncthreads();   // all s_ao/vt/p reads done before s_h overwrites R1/R2

  // ---------------- LN2 in place on s_a (own-wave rows) ----
  layernorm(s_a, n2g, n2b);

  // ---------------- fc1 + GELU -> s_h[128][200] (own-wave rows) ----
  {
    short8 C0[2], C1[2], C2[2];
    #pragma unroll
    for (int wv = 0; wv < 2; wv++){
      const bf16* cp = s_a + (wv*64 + m0 + l15)*104 + quad*8;
      C0[wv] = *(const short8*)(cp);
      C1[wv] = *(const short8*)(cp + 32);
      C2[wv] = *(const short8*)(cp + 64);
    }
    #pragma unroll
    for (int nt = 0; nt < 12; nt++){
      const int wrow = nt*16 + l15;
      short8 w0, w1, w2;
      if constexpr (PRE){
        const bf16* wp = wF1 + wrow*96 + quad*8;
        w0 = *(const short8*)(wp);
        w1 = *(const short8*)(wp + 32);
        w2 = *(const short8*)(wp + 64);
      } else {
        const float* wp = fc1w + wrow*96 + quad*8;
        w0 = ldw8(wp); w1 = ldw8(wp + 32); w2 = ldw8(wp + 64);
      }
      const float bias = fc1b[wrow];
      const f32x4 bacc = {bias, bias, bias, bias};
      #pragma unroll
      for (int wv = 0; wv < 2; wv++){
        f32x4 acc = bacc;
        acc = MFMA16(C0[wv], w0, acc);
        acc = MFMA16(C1[wv], w1, acc);
        acc = MFMA16(C2[wv], w2, acc);
        #pragma unroll
        for (int r = 0; r < 4; r++){
          const float v = acc[r];
          // GELU via tanh identity: g = v - v/(e^{2y}+1), y = 0.7978845608*(v+0.044715 v^3)
          const float t = __expf(1.5957691216057308f * (v + 0.044715f*v*v*v));
          const float g = v - v * (1.f / (t + 1.f));
          s_h[(wv*64 + row0 + r)*200 + wrow] = f2b(g);
        }
      }
    }
  }
  __syncthreads();   // all waves' s_a reads done before s_at overwrites R0

  // ---------------- fc2: K=192 -> s_at transposed [96][136] ----
  {
    short8 F[2][6];
    #pragma unroll
    for (int wv = 0; wv < 2; wv++)
      #pragma unroll
      for (int ks = 0; ks < 6; ks++)
        F[wv][ks] = *(const short8*)(s_h + (wv*64 + m0 + l15)*200 + ks*32 + quad*8);
    #pragma unroll
    for (int nt = 0; nt < 6; nt++){
      const int wrow = nt*16 + l15;
      short8 w[6];
      if constexpr (PRE){
        const bf16* wp = wF2 + wrow*192 + quad*8;
        #pragma unroll
        for (int ks = 0; ks < 6; ks++) w[ks] = *(const short8*)(wp + ks*32);
      } else {
        const float* wp = fc2w + wrow*192 + quad*8;
        #pragma unroll
        for (int ks = 0; ks < 6; ks++) w[ks] = ldw8(wp + ks*32);
      }
      const float bias = fc2b[wrow];
      const f32x4 bacc = {bias, bias, bias, bias};
      #pragma unroll
      for (int wv = 0; wv < 2; wv++){
        f32x4 acc = bacc;
        #pragma unroll
        for (int ks = 0; ks < 6; ks++)
          acc = MFMA16(F[wv][ks], w[ks], acc);
        short4v pk;
        #pragma unroll
        for (int r = 0; r < 4; r++) pk[r] = f2s(acc[r]);
        *(short4v*)(s_at + wrow*136 + wv*64 + row0) = pk;   // [c][token]
      }
    }
  }
  __syncthreads();

  // ---------------- writeout: fp32 residual add from registers, window merge ----
  #pragma unroll
  for (int it = 0; it < 12; it++){
    const int idx4 = it*256 + tid;
    const int c = idx4 >> 5, r = idx4 & 31;
    const int irow = r >> 2, j0 = (r & 3) * 4;
    const int t0 = (j0 >> 3)*64 + irow*8 + (j0 & 7);
    const short4v pv = *(const short4v*)(s_at + c*136 + t0);
    const size_t g = base + (size_t)c*65536 + irow*256 + j0;
    const float4 xv = xsave[it];
    float4 ov;
    ov.x = xv.x + s2f(pv[0]);
    ov.y = xv.y + s2f(pv[1]);
    ov.z = xv.z + s2f(pv[2]);
    ov.w = xv.w + s2f(pv[3]);
    *(float4*)(out + g) = ov;
  }
}

extern "C" void kernel_launch(void* const* d_in, const int* in_sizes, int n_in,
                              void* d_out, int out_size, void* d_ws, size_t ws_size,
                              hipStream_t stream) {
  const float* x     = (const float*)d_in[0];
  const float* qkvw  = (const float*)d_in[1];
  const float* qkvb  = (const float*)d_in[2];
  const float* projw = (const float*)d_in[3];
  const float* projb = (const float*)d_in[4];
  const float* rpb   = (const float*)d_in[5];
  const float* n1g   = (const float*)d_in[6];
  const float* n1b   = (const float*)d_in[7];
  const float* n2g   = (const float*)d_in[8];
  const float* n2b   = (const float*)d_in[9];
  const float* fc1w  = (const float*)d_in[10];
  const float* fc1b  = (const float*)d_in[11];
  const float* fc2w  = (const float*)d_in[12];
  const float* fc2b  = (const float*)d_in[13];
  float* out = (float*)d_out;

  if (ws_size >= WS_NEEDED && d_ws != nullptr) {
    bf16*  wbf  = (bf16*)d_ws;
    float* btab = (float*)((char*)d_ws + BTAB_BYTE_OFF);
    init_ws_kernel<<<dim3(288), dim3(256), 0, stream>>>(
        qkvw, projw, fc1w, fc2w, rpb, wbf, btab);
    swin_block_kernel<true><<<dim3(4096), dim3(TPB), 0, stream>>>(
        x, qkvw, qkvb, projw, projb, rpb,
        n1g, n1b, n2g, n2b, fc1w, fc1b, fc2w, fc2b, out, wbf, btab);
  } else {
    swin_block_kernel<false><<<dim3(4096), dim3(TPB), 0, stream>>>(
        x, qkvw, qkvb, projw, projb, rpb,
        n1g, n1b, n2g, n2b, fc1w, fc1b, fc2w, fc2b, out,
        (const bf16*)nullptr, (const float*)nullptr);
  }
}